// Round 10
// baseline (320.672 us; speedup 1.0000x reference)
//
#include <hip/hip_runtime.h>

#define NN 512

typedef __attribute__((ext_vector_type(8))) short bf16x8;
typedef __attribute__((ext_vector_type(4))) float f32x4;

__device__ __forceinline__ unsigned short f2bf(float x) {
    union { float f; unsigned u; } c; c.f = x;
    unsigned u = c.u + 0x7fffu + ((c.u >> 16) & 1u);
    return (unsigned short)(u >> 16);
}

__device__ __forceinline__ float blo(unsigned u) {
    union { unsigned x; float f; } c; c.x = u << 16; return c.f;
}
__device__ __forceinline__ float bhi(unsigned u) {
    union { unsigned x; float f; } c; c.x = u & 0xffff0000u; return c.f;
}

// sum 5 packed bf16-pairs in fp32, relu, repack
__device__ __forceinline__ unsigned pk2(unsigned a, unsigned b, unsigned c,
                                        unsigned d, unsigned e) {
    float lo = blo(a) + blo(b) + blo(c) + blo(d) + blo(e);
    float hi = bhi(a) + bhi(b) + bhi(c) + bhi(d) + bhi(e);
    lo = fmaxf(lo, 0.0f);
    hi = fmaxf(hi, 0.0f);
    return (unsigned)f2bf(lo) | ((unsigned)f2bf(hi) << 16);
}

__device__ __forceinline__ int find_bin(float d) {
    int bin = 22;  // 22 = "no bin" (zero row in WdTb/WscTb)
    #pragma unroll
    for (int k = 0; k < 22; ++k) {
        float lo = (float)(1e-3 + k * ((20.0 - 1e-3) / 21.0));
        float hi = (k < 21) ? (float)(1e-3 + (k + 1) * ((20.0 - 1e-3) / 21.0)) : 1e8f;
        if (d > lo && d < hi) bin = k;
    }
    return bin;
}

// ---- fused prep: bf16 W1-column gathers, W2/W3 MFMA-fragment packs,
//      bf16 relpos table, p_i node embed, per-pair distogram bin table ----
__global__ __launch_bounds__(128) void k_prep(
        const float* __restrict__ s, const float* __restrict__ t,
        const float* __restrict__ sct,
        const float* __restrict__ Wsp, const float* __restrict__ bsp,
        const float* __restrict__ Wrp, const float* __restrict__ brp,
        const float* __restrict__ W1, const float* __restrict__ b1,
        const float* __restrict__ W2, const float* __restrict__ W3,
        float* __restrict__ p_i, unsigned short* __restrict__ relTb,
        unsigned short* __restrict__ WdTb, unsigned short* __restrict__ WscTb,
        unsigned short* __restrict__ w2a, unsigned short* __restrict__ w3a,
        unsigned short* __restrict__ binT)
{
    __shared__ float sh[2][256];
    const int blk = blockIdx.x, tid = threadIdx.x;

    if (blk < 23) {
        const int bin = blk, c = tid;
        WdTb[bin * 128 + c]  = (bin < 22) ? f2bf(W1[c * 236 + 192 + bin]) : (unsigned short)0;
        WscTb[bin * 128 + c] = (bin < 22) ? f2bf(W1[c * 236 + 214 + bin]) : (unsigned short)0;
    } else if (blk < 55) {
        // pack W2/W3 into A-fragment order: entry idx = ct*256 + ks*64 + lane
        // holds W[ct*16 + (lane&15)][ks*32 + (lane>>4)*8 + e]
        const int seg = blk - 23;
        const int isW3 = seg >> 4;
        const int idx = (seg & 15) * 128 + tid;
        const int lane = idx & 63, ks = (idx >> 6) & 3, ct = idx >> 8;
        const float* W = isW3 ? W3 : W2;
        unsigned short* dst = isW3 ? w3a : w2a;
        const float* wp = W + (ct * 16 + (lane & 15)) * 128 + ks * 32 + (lane >> 4) * 8;
        unsigned r0 = (unsigned)f2bf(wp[0]) | ((unsigned)f2bf(wp[1]) << 16);
        unsigned r1 = (unsigned)f2bf(wp[2]) | ((unsigned)f2bf(wp[3]) << 16);
        unsigned r2 = (unsigned)f2bf(wp[4]) | ((unsigned)f2bf(wp[5]) << 16);
        unsigned r3 = (unsigned)f2bf(wp[6]) | ((unsigned)f2bf(wp[7]) << 16);
        uint4 v = { r0, r1, r2, r3 };
        *(uint4*)(dst + idx * 8) = v;
    } else if (blk < 1078) {
        // relTb[d] = bf16( (pos_emb(d) @ W_rp^T + b_rp) @ W1[:,128:192]^T + b1 )
        const int row = blk - 55;
        const float d = (float)(row - 511);
        if (tid < 32) {
            float f = powf(2056.0f, (float)tid * (1.0f / 32.0f));
            float ang = d * 3.14159265358979323846f / f;
            sh[0][tid] = sinf(ang);
            sh[0][tid + 32] = cosf(ang);
        }
        __syncthreads();
        if (tid < 64) {
            const float* wr = Wrp + tid * 64;
            float a = brp[tid];
            #pragma unroll
            for (int k = 0; k < 64; ++k) a += sh[0][k] * wr[k];
            sh[1][tid] = a;
        }
        __syncthreads();
        const float* w = W1 + tid * 236 + 128;
        float a = b1[tid];
        #pragma unroll
        for (int k = 0; k < 64; ++k) a += sh[1][k] * w[k];
        relTb[row * 128 + tid] = f2bf(a);
    } else if (blk < 1590) {
        // p_i = s @ Wsp^T + bsp, two rows per block
        const int half = tid >> 6, ch = tid & 63;
        const int row = (blk - 1078) * 2 + half;
        *(float4*)&sh[half][ch * 4] = *(const float4*)&s[row * 256 + ch * 4];
        __syncthreads();
        const float* w = Wsp + ch * 256;
        float acc = bsp[ch];
        #pragma unroll 8
        for (int k = 0; k < 256; k += 4)
            acc += sh[half][k]*w[k] + sh[half][k+1]*w[k+1] + sh[half][k+2]*w[k+2] + sh[half][k+3]*w[k+3];
        p_i[row * 64 + ch] = acc;
    } else {
        const int pair = (blk - 1590) * 128 + tid;
        const int bi = pair >> 9, j = pair & (NN - 1);
        const int rj = (bi & ~(NN - 1)) + j;
        float ax = t[bi*3+0] - t[rj*3+0];
        float ay = t[bi*3+1] - t[rj*3+1];
        float az = t[bi*3+2] - t[rj*3+2];
        int bD = find_bin(sqrtf(ax*ax + ay*ay + az*az));
        float sx = sct[bi*3+0] - sct[rj*3+0];
        float sy = sct[bi*3+1] - sct[rj*3+1];
        float sz = sct[bi*3+2] - sct[rj*3+2];
        int bS = find_bin(sqrtf(sx*sx + sy*sy + sz*sz));
        binT[pair] = (unsigned short)(bD | (bS << 5));
    }
}

// ---- qL/qR (bf16): per-node contributions through W1 cols [0:64)/[64:128) ----
__global__ __launch_bounds__(128) void k_ql(const float* __restrict__ p_i,
        const float* __restrict__ W1,
        unsigned short* __restrict__ qLb, unsigned short* __restrict__ qRb)
{
    __shared__ float pr[64];
    const int row = blockIdx.x, tid = threadIdx.x;
    if (tid < 16) *(float4*)&pr[tid * 4] = *(const float4*)&p_i[row * 64 + tid * 4];
    __syncthreads();
    const float* w = W1 + tid * 236;
    float aL = 0.f, aR = 0.f;
    #pragma unroll
    for (int k = 0; k < 64; ++k) { aL += pr[k] * w[k]; aR += pr[k] * w[64 + k]; }
    qLb[row * 128 + tid] = f2bf(aL);
    qRb[row * 128 + tid] = f2bf(aR);
}

// LDS layout (bytes):
#define H1_OFF  0        // 64 rows x 256B bf16, XOR-swizzled; reused as out-stage
#define H2_OFF  16384    // 64 rows x 256B bf16, XOR-swizzled; reused as out-stage
#define LNP_OFF 32768    // 64 rows x 48B (4 wc float2 partials, stride 12 f)
#define SMEM_SZ 35840

// ---- main fused kernel: 1 block per (b,i); weights loaded to regs ONCE,
//      then loop over 8 j-subtiles of 64 rows. 8 waves = 2 row-halves x
//      4 ch-quarters, 2 ct per wave (2x B-frag reuse). h1/h2 in LDS;
//      LN via cross-wave partials; LDS-bounced full-line stores. ----
__global__ __launch_bounds__(512, 4) void k_main(
    const float* __restrict__ pmask,
    const unsigned short* __restrict__ qLb, const unsigned short* __restrict__ qRb,
    const unsigned short* __restrict__ relTb, const unsigned short* __restrict__ WdTb,
    const unsigned short* __restrict__ WscTb, const unsigned short* __restrict__ binT,
    const unsigned short* __restrict__ w2a, const unsigned short* __restrict__ w3a,
    const float* __restrict__ b2, const float* __restrict__ b3,
    const float* __restrict__ lng, const float* __restrict__ lnb,
    float* __restrict__ out)
{
    __shared__ __align__(16) char smem[SMEM_SZ];

    const int tid  = threadIdx.x;
    const int l    = tid & 63;
    const int w    = tid >> 6;
    const int wr   = w >> 2;         // row half (32 rows)
    const int wc   = w & 3;          // channel quarter (32 ch = 2 ct)
    const int jloc = l & 15;
    const int gq   = l >> 4;

    const int bi    = blockIdx.x;            // b*512 + i
    const int i     = bi & (NN - 1);
    const int bbase = bi & ~(NN - 1);

    // ---- per-block prologue: weight fragments into registers (once) ----
    bf16x8 w2r[2][4], w3r[2][4];
    #pragma unroll
    for (int cc = 0; cc < 2; ++cc)
        #pragma unroll
        for (int ks = 0; ks < 4; ++ks) {
            const int fi = ((wc * 2 + cc) * 256 + ks * 64 + l) * 8;
            w2r[cc][ks] = *(const bf16x8*)(w2a + fi);
            w3r[cc][ks] = *(const bf16x8*)(w3a + fi);
        }

    const int rswz = (jloc & 7) << 4;
    const int hr   = tid >> 3;               // h1-build: row 0..63
    const int hq   = tid & 7;                // h1-build: ch-octet 0..7
    const unsigned short* qLp = qLb + (size_t)bi * 128;

    for (int jt = 0; jt < 8; ++jt) {
        const int j0 = jt * 64;

        float maskv[2];
        #pragma unroll
        for (int rt = 0; rt < 2; ++rt)
            maskv[rt] = pmask[(size_t)bi * NN + j0 + wr * 32 + rt * 16 + jloc];

        // ---- build h1 = relu(qL+qR+relT+Wd[bin]+Wsc[bin]) into LDS (bf16) ----
        {
            const unsigned bv = binT[bi * NN + j0 + hr];
            const int bD = bv & 31, bS = (int)(bv >> 5);
            const unsigned short* qRp = qRb + (size_t)(bbase + j0 + hr) * 128;
            const unsigned short* rTp = relTb + (size_t)(i - (j0 + hr) + NN - 1) * 128;
            const unsigned short* dTp = WdTb + bD * 128;
            const unsigned short* sTp = WscTb + bS * 128;
            const int hswz = (hr & 7) << 4;
            #pragma unroll
            for (int u = 0; u < 2; ++u) {
                const int c0 = hq * 16 + u * 8;
                uint4 A = *(const uint4*)(qLp + c0);
                uint4 B = *(const uint4*)(qRp + c0);
                uint4 C = *(const uint4*)(rTp + c0);
                uint4 D = *(const uint4*)(dTp + c0);
                uint4 E = *(const uint4*)(sTp + c0);
                uint4 P;
                P.x = pk2(A.x, B.x, C.x, D.x, E.x);
                P.y = pk2(A.y, B.y, C.y, D.y, E.y);
                P.z = pk2(A.z, B.z, C.z, D.z, E.z);
                P.w = pk2(A.w, B.w, C.w, D.w, E.w);
                *(uint4*)(smem + H1_OFF + ((hr * 256 + c0 * 2) ^ hswz)) = P;
            }
        }
        __syncthreads();   // bar1: h1 complete

        // ---- GEMM2: 32 rows x 32 ch per wave; each B-frag feeds 2 MFMA ----
        #pragma unroll
        for (int rt = 0; rt < 2; ++rt) {
            const int rowb = (wr * 32 + rt * 16 + jloc) * 256;
            f32x4 a2[2] = { {0.f,0.f,0.f,0.f}, {0.f,0.f,0.f,0.f} };
            #pragma unroll
            for (int ks = 0; ks < 4; ++ks) {
                bf16x8 bfr = *(bf16x8*)(smem + H1_OFF + ((rowb + ks * 64 + gq * 16) ^ rswz));
                a2[0] = __builtin_amdgcn_mfma_f32_16x16x32_bf16(w2r[0][ks], bfr, a2[0], 0, 0, 0);
                a2[1] = __builtin_amdgcn_mfma_f32_16x16x32_bf16(w2r[1][ks], bfr, a2[1], 0, 0, 0);
            }
            #pragma unroll
            for (int cc = 0; cc < 2; ++cc) {
                const int c = wc * 32 + cc * 16 + gq * 4;
                float4 bb = *(const float4*)(b2 + c);
                float y0 = fmaxf(a2[cc][0] + bb.x, 0.0f);
                float y1 = fmaxf(a2[cc][1] + bb.y, 0.0f);
                float y2 = fmaxf(a2[cc][2] + bb.z, 0.0f);
                float y3 = fmaxf(a2[cc][3] + bb.w, 0.0f);
                uint2 pk;
                pk.x = (unsigned)f2bf(y0) | ((unsigned)f2bf(y1) << 16);
                pk.y = (unsigned)f2bf(y2) | ((unsigned)f2bf(y3) << 16);
                *(uint2*)(smem + H2_OFF + ((rowb + c * 2) ^ rswz)) = pk;
            }
        }
        __syncthreads();   // bar2: h2 complete

        // ---- GEMM3 + cross-wave LN partials ----
        f32x4 acc3[2][2];
        float* lnp = (float*)(smem + LNP_OFF);
        #pragma unroll
        for (int rt = 0; rt < 2; ++rt) {
            const int rowb = (wr * 32 + rt * 16 + jloc) * 256;
            f32x4 a3[2] = { {0.f,0.f,0.f,0.f}, {0.f,0.f,0.f,0.f} };
            #pragma unroll
            for (int ks = 0; ks < 4; ++ks) {
                bf16x8 bfr = *(bf16x8*)(smem + H2_OFF + ((rowb + ks * 64 + gq * 16) ^ rswz));
                a3[0] = __builtin_amdgcn_mfma_f32_16x16x32_bf16(w3r[0][ks], bfr, a3[0], 0, 0, 0);
                a3[1] = __builtin_amdgcn_mfma_f32_16x16x32_bf16(w3r[1][ks], bfr, a3[1], 0, 0, 0);
            }
            float s1 = 0.f, s2 = 0.f;
            #pragma unroll
            for (int cc = 0; cc < 2; ++cc) {
                const int c = wc * 32 + cc * 16 + gq * 4;
                float4 bb = *(const float4*)(b3 + c);
                a3[cc][0] += bb.x; a3[cc][1] += bb.y;
                a3[cc][2] += bb.z; a3[cc][3] += bb.w;
                acc3[cc][rt] = a3[cc];
                #pragma unroll
                for (int r = 0; r < 4; ++r) { float v = a3[cc][r]; s1 += v; s2 += v * v; }
            }
            s1 += __shfl_xor(s1, 16); s2 += __shfl_xor(s2, 16);
            s1 += __shfl_xor(s1, 32); s2 += __shfl_xor(s2, 32);
            if (l < 16) {
                const int row = wr * 32 + rt * 16 + jloc;
                *(float2*)(lnp + row * 12 + wc * 2) = make_float2(s1, s2);
            }
        }
        __syncthreads();   // bar3: LN partials done; h1/h2 reads drained

        // ---- finish LN, scale, mask, write to out-stage (swizzled slots) ----
        #pragma unroll
        for (int rt = 0; rt < 2; ++rt) {
            const int row = wr * 32 + rt * 16 + jloc;
            float4 v0 = *(float4*)(lnp + row * 12);
            float4 v1 = *(float4*)(lnp + row * 12 + 4);
            const float s1 = v0.x + v0.z + v1.x + v1.z;
            const float s2 = v0.y + v0.w + v1.y + v1.w;
            const float mean = s1 * (1.0f / 128.0f);
            const float var  = s2 * (1.0f / 128.0f) - mean * mean;
            const float rstd = rsqrtf(var + 1e-5f);
            const float mk = maskv[rt];
            #pragma unroll
            for (int cc = 0; cc < 2; ++cc) {
                const int c = wc * 32 + cc * 16 + gq * 4;
                float4 g4  = *(const float4*)(lng + c);
                float4 be4 = *(const float4*)(lnb + c);
                f32x4 a3 = acc3[cc][rt];
                f32x4 o;
                o[0] = ((a3[0] - mean) * rstd * g4.x + be4.x) * mk;
                o[1] = ((a3[1] - mean) * rstd * g4.y + be4.y) * mk;
                o[2] = ((a3[2] - mean) * rstd * g4.z + be4.z) * mk;
                o[3] = ((a3[3] - mean) * rstd * g4.w + be4.w) * mk;
                const int slot = (wc * 8 + cc * 4 + gq) ^ (row & 31);
                *(f32x4*)(smem + row * 512 + slot * 16) = o;
            }
        }
        __syncthreads();   // bar4: out-stage complete

        // ---- block-wide coalesced copy: 4 x 8KB, 1KB contiguous per wave ----
        float* ob = out + ((size_t)(bi * NN + j0)) * 128;
        #pragma unroll
        for (int it = 0; it < 4; ++it) {
            const int boff = it * 8192 + tid * 16;      // linear byte offset
            const int row  = boff >> 9;
            const int slot = (boff >> 4) & 31;
            const int sslt = slot ^ (row & 31);
            f32x4 v = *(f32x4*)(smem + row * 512 + sslt * 16);
            __builtin_nontemporal_store(v, (f32x4*)(ob + (boff >> 2)));
        }
        __syncthreads();   // bar5: out-stage reads done before next h1 write
    }
}

extern "C" void kernel_launch(void* const* d_in, const int* in_sizes, int n_in,
                              void* d_out, int out_size, void* d_ws, size_t ws_size,
                              hipStream_t stream)
{
    const float* s   = (const float*)d_in[0];
    const float* t   = (const float*)d_in[1];
    const float* sct = (const float*)d_in[2];
    const float* pm  = (const float*)d_in[3];
    const float* Wsp = (const float*)d_in[4];
    const float* bsp = (const float*)d_in[5];
    const float* Wrp = (const float*)d_in[6];
    const float* brp = (const float*)d_in[7];
    const float* W1  = (const float*)d_in[8];
    const float* b1  = (const float*)d_in[9];
    const float* W2  = (const float*)d_in[10];
    const float* b2  = (const float*)d_in[11];
    const float* W3  = (const float*)d_in[12];
    const float* b3  = (const float*)d_in[13];
    const float* lng = (const float*)d_in[14];
    const float* lnb = (const float*)d_in[15];

    float* ws = (float*)d_ws;
    float*          p_i   = ws;                                   // 65536 f
    unsigned short* qLb   = (unsigned short*)(ws + 65536);        // 131072 u16
    unsigned short* qRb   = (unsigned short*)(ws + 131072);       // 131072 u16
    unsigned short* relTb = (unsigned short*)(ws + 196608);       // 130944 u16
    unsigned short* WdTb  = (unsigned short*)(ws + 262144);       // 2944 u16
    unsigned short* WscTb = (unsigned short*)(ws + 263616);       // 2944 u16
    unsigned short* w2a   = (unsigned short*)(ws + 265088);       // 16384 u16
    unsigned short* w3a   = (unsigned short*)(ws + 273280);       // 16384 u16
    unsigned short* binT  = (unsigned short*)(ws + 281472);       // 524288 u16

    k_prep<<<5686, 128, 0, stream>>>(s, t, sct, Wsp, bsp, Wrp, brp, W1, b1, W2, W3,
                                     p_i, relTb, WdTb, WscTb, w2a, w3a, binT);
    k_ql<<<1024, 128, 0, stream>>>(p_i, W1, qLb, qRb);
    k_main<<<1024, 512, 0, stream>>>(pm, qLb, qRb, relTb, WdTb, WscTb, binT,
                                     w2a, w3a, b2, b3, lng, lnb, (float*)d_out);
}

// Round 11
// 268.372 us; speedup vs baseline: 1.1949x; 1.1949x over previous
//
#include <hip/hip_runtime.h>

#define NN 512

typedef __attribute__((ext_vector_type(8))) short bf16x8;
typedef __attribute__((ext_vector_type(4))) float f32x4;

__device__ __forceinline__ unsigned short f2bf(float x) {
    union { float f; unsigned u; } c; c.f = x;
    unsigned u = c.u + 0x7fffu + ((c.u >> 16) & 1u);
    return (unsigned short)(u >> 16);
}

__device__ __forceinline__ float blo(unsigned u) {
    union { unsigned x; float f; } c; c.x = u << 16; return c.f;
}
__device__ __forceinline__ float bhi(unsigned u) {
    union { unsigned x; float f; } c; c.x = u & 0xffff0000u; return c.f;
}

// sum 5 packed bf16-pairs in fp32, relu, repack
__device__ __forceinline__ unsigned pk2(unsigned a, unsigned b, unsigned c,
                                        unsigned d, unsigned e) {
    float lo = blo(a) + blo(b) + blo(c) + blo(d) + blo(e);
    float hi = bhi(a) + bhi(b) + bhi(c) + bhi(d) + bhi(e);
    lo = fmaxf(lo, 0.0f);
    hi = fmaxf(hi, 0.0f);
    return (unsigned)f2bf(lo) | ((unsigned)f2bf(hi) << 16);
}

// O(1) bin: float estimate, then exact predicate on k-1..k+1
__device__ __forceinline__ int find_bin(float d) {
    const float stepf   = (float)((20.0 - 1e-3) / 21.0);
    const float invstep = (float)(21.0 / (20.0 - 1e-3));
    int kc = (int)floorf((d - 1e-3f) * invstep);
    int bin = 22;  // 22 = "no bin" (zero row in WdTb/WscTb)
    #pragma unroll
    for (int dk = -1; dk <= 1; ++dk) {
        int k = kc + dk;
        if (k >= 0 && k <= 21) {
            float lo = fmaf((float)k, stepf, 1e-3f);
            float hi = (k < 21) ? fmaf((float)(k + 1), stepf, 1e-3f) : 1e8f;
            if (d > lo && d < hi) bin = k;
        }
    }
    return bin;
}

// ---- fused prep: bf16 W1-column gathers, W2/W3 MFMA-fragment packs,
//      bf16 relpos table, p_i node embed, per-pair distogram bin table ----
__global__ __launch_bounds__(128) void k_prep(
        const float* __restrict__ s, const float* __restrict__ t,
        const float* __restrict__ sct,
        const float* __restrict__ Wsp, const float* __restrict__ bsp,
        const float* __restrict__ Wrp, const float* __restrict__ brp,
        const float* __restrict__ W1, const float* __restrict__ b1,
        const float* __restrict__ W2, const float* __restrict__ W3,
        float* __restrict__ p_i, unsigned short* __restrict__ relTb,
        unsigned short* __restrict__ WdTb, unsigned short* __restrict__ WscTb,
        unsigned short* __restrict__ w2a, unsigned short* __restrict__ w3a,
        unsigned short* __restrict__ binT)
{
    __shared__ float sh[2][256];
    const int blk = blockIdx.x, tid = threadIdx.x;

    if (blk < 23) {
        const int bin = blk, c = tid;
        WdTb[bin * 128 + c]  = (bin < 22) ? f2bf(W1[c * 236 + 192 + bin]) : (unsigned short)0;
        WscTb[bin * 128 + c] = (bin < 22) ? f2bf(W1[c * 236 + 214 + bin]) : (unsigned short)0;
    } else if (blk < 55) {
        // pack W2/W3 into A-fragment order: entry idx = ct*256 + ks*64 + lane
        // holds W[ct*16 + (lane&15)][ks*32 + (lane>>4)*8 + e]
        const int seg = blk - 23;
        const int isW3 = seg >> 4;
        const int idx = (seg & 15) * 128 + tid;
        const int lane = idx & 63, ks = (idx >> 6) & 3, ct = idx >> 8;
        const float* W = isW3 ? W3 : W2;
        unsigned short* dst = isW3 ? w3a : w2a;
        const float* wp = W + (ct * 16 + (lane & 15)) * 128 + ks * 32 + (lane >> 4) * 8;
        unsigned r0 = (unsigned)f2bf(wp[0]) | ((unsigned)f2bf(wp[1]) << 16);
        unsigned r1 = (unsigned)f2bf(wp[2]) | ((unsigned)f2bf(wp[3]) << 16);
        unsigned r2 = (unsigned)f2bf(wp[4]) | ((unsigned)f2bf(wp[5]) << 16);
        unsigned r3 = (unsigned)f2bf(wp[6]) | ((unsigned)f2bf(wp[7]) << 16);
        uint4 v = { r0, r1, r2, r3 };
        *(uint4*)(dst + idx * 8) = v;
    } else if (blk < 1078) {
        // relTb[d] = bf16( (pos_emb(d) @ W_rp^T + b_rp) @ W1[:,128:192]^T + b1 )
        const int row = blk - 55;
        const float d = (float)(row - 511);
        if (tid < 32) {
            float f = powf(2056.0f, (float)tid * (1.0f / 32.0f));
            float ang = d * 3.14159265358979323846f / f;
            sh[0][tid] = sinf(ang);
            sh[0][tid + 32] = cosf(ang);
        }
        __syncthreads();
        if (tid < 64) {
            const float* wr = Wrp + tid * 64;
            float a = brp[tid];
            #pragma unroll
            for (int k = 0; k < 64; ++k) a += sh[0][k] * wr[k];
            sh[1][tid] = a;
        }
        __syncthreads();
        const float* w = W1 + tid * 236 + 128;
        float a = b1[tid];
        #pragma unroll
        for (int k = 0; k < 64; ++k) a += sh[1][k] * w[k];
        relTb[row * 128 + tid] = f2bf(a);
    } else if (blk < 1590) {
        // p_i = s @ Wsp^T + bsp, two rows per block
        const int half = tid >> 6, ch = tid & 63;
        const int row = (blk - 1078) * 2 + half;
        *(float4*)&sh[half][ch * 4] = *(const float4*)&s[row * 256 + ch * 4];
        __syncthreads();
        const float* w = Wsp + ch * 256;
        float acc = bsp[ch];
        #pragma unroll 8
        for (int k = 0; k < 256; k += 4)
            acc += sh[half][k]*w[k] + sh[half][k+1]*w[k+1] + sh[half][k+2]*w[k+2] + sh[half][k+3]*w[k+3];
        p_i[row * 64 + ch] = acc;
    } else {
        const int pair = (blk - 1590) * 128 + tid;
        const int bi = pair >> 9, j = pair & (NN - 1);
        const int rj = (bi & ~(NN - 1)) + j;
        float ax = t[bi*3+0] - t[rj*3+0];
        float ay = t[bi*3+1] - t[rj*3+1];
        float az = t[bi*3+2] - t[rj*3+2];
        int bD = find_bin(sqrtf(ax*ax + ay*ay + az*az));
        float sx = sct[bi*3+0] - sct[rj*3+0];
        float sy = sct[bi*3+1] - sct[rj*3+1];
        float sz = sct[bi*3+2] - sct[rj*3+2];
        int bS = find_bin(sqrtf(sx*sx + sy*sy + sz*sz));
        binT[pair] = (unsigned short)(bD | (bS << 5));
    }
}

// ---- qL/qR (bf16): per-node contributions through W1 cols [0:64)/[64:128) ----
__global__ __launch_bounds__(128) void k_ql(const float* __restrict__ p_i,
        const float* __restrict__ W1,
        unsigned short* __restrict__ qLb, unsigned short* __restrict__ qRb)
{
    __shared__ float pr[64];
    const int row = blockIdx.x, tid = threadIdx.x;
    if (tid < 16) *(float4*)&pr[tid * 4] = *(const float4*)&p_i[row * 64 + tid * 4];
    __syncthreads();
    const float* w = W1 + tid * 236;
    float aL = 0.f, aR = 0.f;
    #pragma unroll
    for (int k = 0; k < 64; ++k) { aL += pr[k] * w[k]; aR += pr[k] * w[64 + k]; }
    qLb[row * 128 + tid] = f2bf(aL);
    qRb[row * 128 + tid] = f2bf(aR);
}

// LDS layout (bytes):
#define H1_OFF  0        // 32 rows x 256B bf16, XOR-swizzled; reused as out-stage
#define H2_OFF  8192     // 32 rows x 256B bf16, XOR-swizzled; reused as out-stage
#define LNP_OFF 16384    // 32 rows x 48B (4 wc float2 partials, stride 12 f)
#define SMEM_SZ 17920

// ---- main fused kernel: 256 thr = 4 waves; block = 32 rows x 128 ch;
//      wave wc owns 2 ct tiles per GEMM in regs (2x B-frag reuse);
//      8 blocks/CU for phase overlap. h1/h2 in LDS; LN cross-wave;
//      LDS-bounced full-line stores. ----
__global__ __launch_bounds__(256, 8) void k_main(
    const float* __restrict__ pmask,
    const unsigned short* __restrict__ qLb, const unsigned short* __restrict__ qRb,
    const unsigned short* __restrict__ relTb, const unsigned short* __restrict__ WdTb,
    const unsigned short* __restrict__ WscTb, const unsigned short* __restrict__ binT,
    const unsigned short* __restrict__ w2a, const unsigned short* __restrict__ w3a,
    const float* __restrict__ b2, const float* __restrict__ b3,
    const float* __restrict__ lng, const float* __restrict__ lnb,
    float* __restrict__ out)
{
    __shared__ __align__(16) char smem[SMEM_SZ];

    const int tid  = threadIdx.x;
    const int l    = tid & 63;
    const int wc   = tid >> 6;       // wave = channel quarter (32 ch = 2 ct)
    const int jloc = l & 15;
    const int gq   = l >> 4;

    const int blk   = blockIdx.x;
    const int bi    = blk >> 4;              // b*512 + i
    const int i     = bi & (NN - 1);
    const int bbase = bi & ~(NN - 1);
    const int j0    = (blk & 15) * 32;       // block covers 32 rows

    // ---- per-wave weight fragments (2 ct per GEMM, in registers) ----
    bf16x8 w2r[2][4], w3r[2][4];
    #pragma unroll
    for (int cc = 0; cc < 2; ++cc)
        #pragma unroll
        for (int ks = 0; ks < 4; ++ks) {
            const int fi = ((wc * 2 + cc) * 256 + ks * 64 + l) * 8;
            w2r[cc][ks] = *(const bf16x8*)(w2a + fi);
            w3r[cc][ks] = *(const bf16x8*)(w3a + fi);
        }
    float maskv[2];
    #pragma unroll
    for (int rt = 0; rt < 2; ++rt)
        maskv[rt] = pmask[(size_t)bi * NN + j0 + rt * 16 + jloc];

    // ---- build h1 = relu(qL+qR+relT+Wd[bin]+Wsc[bin]) into LDS (bf16) ----
    {
        const int hr = tid >> 3, hq = tid & 7;      // row 0..31, ch-octet 0..7
        const unsigned bv = binT[bi * NN + j0 + hr];
        const int bD = bv & 31, bS = (int)(bv >> 5);
        const unsigned short* qLp = qLb + (size_t)bi * 128;
        const unsigned short* qRp = qRb + (size_t)(bbase + j0 + hr) * 128;
        const unsigned short* rTp = relTb + (size_t)(i - (j0 + hr) + NN - 1) * 128;
        const unsigned short* dTp = WdTb + bD * 128;
        const unsigned short* sTp = WscTb + bS * 128;
        const int hswz = (hr & 7) << 4;
        #pragma unroll
        for (int u = 0; u < 2; ++u) {
            const int c0 = hq * 16 + u * 8;
            uint4 A = *(const uint4*)(qLp + c0);
            uint4 B = *(const uint4*)(qRp + c0);
            uint4 C = *(const uint4*)(rTp + c0);
            uint4 D = *(const uint4*)(dTp + c0);
            uint4 E = *(const uint4*)(sTp + c0);
            uint4 P;
            P.x = pk2(A.x, B.x, C.x, D.x, E.x);
            P.y = pk2(A.y, B.y, C.y, D.y, E.y);
            P.z = pk2(A.z, B.z, C.z, D.z, E.z);
            P.w = pk2(A.w, B.w, C.w, D.w, E.w);
            *(uint4*)(smem + H1_OFF + ((hr * 256 + c0 * 2) ^ hswz)) = P;
        }
    }
    __syncthreads();   // bar1: h1 complete

    const int rswz = (jloc & 7) << 4;

    // ---- GEMM2: wave computes 32 rows x 32 ch; each B-frag feeds 2 MFMA ----
    #pragma unroll
    for (int rt = 0; rt < 2; ++rt) {
        const int rowb = (rt * 16 + jloc) * 256;
        f32x4 a2[2] = { {0.f,0.f,0.f,0.f}, {0.f,0.f,0.f,0.f} };
        #pragma unroll
        for (int ks = 0; ks < 4; ++ks) {
            bf16x8 bfr = *(bf16x8*)(smem + H1_OFF + ((rowb + ks * 64 + gq * 16) ^ rswz));
            a2[0] = __builtin_amdgcn_mfma_f32_16x16x32_bf16(w2r[0][ks], bfr, a2[0], 0, 0, 0);
            a2[1] = __builtin_amdgcn_mfma_f32_16x16x32_bf16(w2r[1][ks], bfr, a2[1], 0, 0, 0);
        }
        #pragma unroll
        for (int cc = 0; cc < 2; ++cc) {
            const int c = wc * 32 + cc * 16 + gq * 4;
            float4 bb = *(const float4*)(b2 + c);
            float y0 = fmaxf(a2[cc][0] + bb.x, 0.0f);
            float y1 = fmaxf(a2[cc][1] + bb.y, 0.0f);
            float y2 = fmaxf(a2[cc][2] + bb.z, 0.0f);
            float y3 = fmaxf(a2[cc][3] + bb.w, 0.0f);
            uint2 pk;
            pk.x = (unsigned)f2bf(y0) | ((unsigned)f2bf(y1) << 16);
            pk.y = (unsigned)f2bf(y2) | ((unsigned)f2bf(y3) << 16);
            *(uint2*)(smem + H2_OFF + ((rowb + c * 2) ^ rswz)) = pk;
        }
    }
    __syncthreads();   // bar2: h2 complete

    // ---- GEMM3 + cross-wave LN partials ----
    f32x4 acc3[2][2];
    float* lnp = (float*)(smem + LNP_OFF);
    #pragma unroll
    for (int rt = 0; rt < 2; ++rt) {
        const int rowb = (rt * 16 + jloc) * 256;
        f32x4 a3[2] = { {0.f,0.f,0.f,0.f}, {0.f,0.f,0.f,0.f} };
        #pragma unroll
        for (int ks = 0; ks < 4; ++ks) {
            bf16x8 bfr = *(bf16x8*)(smem + H2_OFF + ((rowb + ks * 64 + gq * 16) ^ rswz));
            a3[0] = __builtin_amdgcn_mfma_f32_16x16x32_bf16(w3r[0][ks], bfr, a3[0], 0, 0, 0);
            a3[1] = __builtin_amdgcn_mfma_f32_16x16x32_bf16(w3r[1][ks], bfr, a3[1], 0, 0, 0);
        }
        float s1 = 0.f, s2 = 0.f;
        #pragma unroll
        for (int cc = 0; cc < 2; ++cc) {
            const int c = wc * 32 + cc * 16 + gq * 4;
            float4 bb = *(const float4*)(b3 + c);
            a3[cc][0] += bb.x; a3[cc][1] += bb.y;
            a3[cc][2] += bb.z; a3[cc][3] += bb.w;
            acc3[cc][rt] = a3[cc];
            #pragma unroll
            for (int r = 0; r < 4; ++r) { float v = a3[cc][r]; s1 += v; s2 += v * v; }
        }
        s1 += __shfl_xor(s1, 16); s2 += __shfl_xor(s2, 16);
        s1 += __shfl_xor(s1, 32); s2 += __shfl_xor(s2, 32);
        if (l < 16) {
            const int row = rt * 16 + jloc;
            *(float2*)(lnp + row * 12 + wc * 2) = make_float2(s1, s2);
        }
    }
    __syncthreads();   // bar3: LN partials done; h1/h2 reads drained

    // ---- finish LN, scale, mask, write to out-stage (swizzled slots) ----
    #pragma unroll
    for (int rt = 0; rt < 2; ++rt) {
        const int row = rt * 16 + jloc;
        float4 v0 = *(float4*)(lnp + row * 12);
        float4 v1 = *(float4*)(lnp + row * 12 + 4);
        const float s1 = v0.x + v0.z + v1.x + v1.z;
        const float s2 = v0.y + v0.w + v1.y + v1.w;
        const float mean = s1 * (1.0f / 128.0f);
        const float var  = s2 * (1.0f / 128.0f) - mean * mean;
        const float rstd = rsqrtf(var + 1e-5f);
        const float mk = maskv[rt];
        #pragma unroll
        for (int cc = 0; cc < 2; ++cc) {
            const int c = wc * 32 + cc * 16 + gq * 4;
            float4 g4  = *(const float4*)(lng + c);
            float4 be4 = *(const float4*)(lnb + c);
            f32x4 a3 = acc3[cc][rt];
            f32x4 o;
            o[0] = ((a3[0] - mean) * rstd * g4.x + be4.x) * mk;
            o[1] = ((a3[1] - mean) * rstd * g4.y + be4.y) * mk;
            o[2] = ((a3[2] - mean) * rstd * g4.z + be4.z) * mk;
            o[3] = ((a3[3] - mean) * rstd * g4.w + be4.w) * mk;
            const int slot = (wc * 8 + cc * 4 + gq) ^ (row & 31);
            *(f32x4*)(smem + row * 512 + slot * 16) = o;
        }
    }
    __syncthreads();   // bar4: out-stage complete

    // ---- block-wide coalesced copy: 4 x 4KB, 1KB contiguous per wave ----
    float* ob = out + ((size_t)(bi * NN + j0)) * 128;
    #pragma unroll
    for (int it = 0; it < 4; ++it) {
        const int boff = it * 4096 + tid * 16;      // linear byte offset
        const int row  = boff >> 9;
        const int slot = (boff >> 4) & 31;
        const int sslt = slot ^ (row & 31);
        f32x4 v = *(f32x4*)(smem + row * 512 + sslt * 16);
        __builtin_nontemporal_store(v, (f32x4*)(ob + (boff >> 2)));
    }
}

extern "C" void kernel_launch(void* const* d_in, const int* in_sizes, int n_in,
                              void* d_out, int out_size, void* d_ws, size_t ws_size,
                              hipStream_t stream)
{
    const float* s   = (const float*)d_in[0];
    const float* t   = (const float*)d_in[1];
    const float* sct = (const float*)d_in[2];
    const float* pm  = (const float*)d_in[3];
    const float* Wsp = (const float*)d_in[4];
    const float* bsp = (const float*)d_in[5];
    const float* Wrp = (const float*)d_in[6];
    const float* brp = (const float*)d_in[7];
    const float* W1  = (const float*)d_in[8];
    const float* b1  = (const float*)d_in[9];
    const float* W2  = (const float*)d_in[10];
    const float* b2  = (const float*)d_in[11];
    const float* W3  = (const float*)d_in[12];
    const float* b3  = (const float*)d_in[13];
    const float* lng = (const float*)d_in[14];
    const float* lnb = (const float*)d_in[15];

    float* ws = (float*)d_ws;
    float*          p_i   = ws;                                   // 65536 f
    unsigned short* qLb   = (unsigned short*)(ws + 65536);        // 131072 u16
    unsigned short* qRb   = (unsigned short*)(ws + 131072);       // 131072 u16
    unsigned short* relTb = (unsigned short*)(ws + 196608);       // 130944 u16
    unsigned short* WdTb  = (unsigned short*)(ws + 262144);       // 2944 u16
    unsigned short* WscTb = (unsigned short*)(ws + 263616);       // 2944 u16
    unsigned short* w2a   = (unsigned short*)(ws + 265088);       // 16384 u16
    unsigned short* w3a   = (unsigned short*)(ws + 273280);       // 16384 u16
    unsigned short* binT  = (unsigned short*)(ws + 281472);       // 524288 u16

    k_prep<<<5686, 128, 0, stream>>>(s, t, sct, Wsp, bsp, Wrp, brp, W1, b1, W2, W3,
                                     p_i, relTb, WdTb, WscTb, w2a, w3a, binT);
    k_ql<<<1024, 128, 0, stream>>>(p_i, W1, qLb, qRb);
    k_main<<<16384, 256, 0, stream>>>(pm, qLb, qRb, relTb, WdTb, WscTb, binT,
                                      w2a, w3a, b2, b3, lng, lnb, (float*)d_out);
}

// Round 12
// 128.522 us; speedup vs baseline: 2.4951x; 2.0881x over previous
//
#include <hip/hip_runtime.h>

#define NN 512

typedef __attribute__((ext_vector_type(8))) short bf16x8;
typedef __attribute__((ext_vector_type(4))) float f32x4;

__device__ __forceinline__ unsigned short f2bf(float x) {
    union { float f; unsigned u; } c; c.f = x;
    unsigned u = c.u + 0x7fffu + ((c.u >> 16) & 1u);
    return (unsigned short)(u >> 16);
}

__device__ __forceinline__ float blo(unsigned u) {
    union { unsigned x; float f; } c; c.x = u << 16; return c.f;
}
__device__ __forceinline__ float bhi(unsigned u) {
    union { unsigned x; float f; } c; c.x = u & 0xffff0000u; return c.f;
}

// sum 5 packed bf16-pairs in fp32, relu, repack
__device__ __forceinline__ unsigned pk2(unsigned a, unsigned b, unsigned c,
                                        unsigned d, unsigned e) {
    float lo = blo(a) + blo(b) + blo(c) + blo(d) + blo(e);
    float hi = bhi(a) + bhi(b) + bhi(c) + bhi(d) + bhi(e);
    lo = fmaxf(lo, 0.0f);
    hi = fmaxf(hi, 0.0f);
    return (unsigned)f2bf(lo) | ((unsigned)f2bf(hi) << 16);
}

// O(1) bin: float estimate, then exact predicate on k-1..k+1 (verified R11)
__device__ __forceinline__ int find_bin(float d) {
    const float stepf   = (float)((20.0 - 1e-3) / 21.0);
    const float invstep = (float)(21.0 / (20.0 - 1e-3));
    int kc = (int)floorf((d - 1e-3f) * invstep);
    int bin = 22;  // 22 = "no bin" (zero row in WdTb/WscTb)
    #pragma unroll
    for (int dk = -1; dk <= 1; ++dk) {
        int k = kc + dk;
        if (k >= 0 && k <= 21) {
            float lo = fmaf((float)k, stepf, 1e-3f);
            float hi = (k < 21) ? fmaf((float)(k + 1), stepf, 1e-3f) : 1e8f;
            if (d > lo && d < hi) bin = k;
        }
    }
    return bin;
}

// ---- fused prep: bf16 W1-column gathers, W2/W3 MFMA-fragment packs,
//      bf16 relpos table, p_i node embed, per-pair distogram bin table ----
__global__ __launch_bounds__(128) void k_prep(
        const float* __restrict__ s, const float* __restrict__ t,
        const float* __restrict__ sct,
        const float* __restrict__ Wsp, const float* __restrict__ bsp,
        const float* __restrict__ Wrp, const float* __restrict__ brp,
        const float* __restrict__ W1, const float* __restrict__ b1,
        const float* __restrict__ W2, const float* __restrict__ W3,
        float* __restrict__ p_i, unsigned short* __restrict__ relTb,
        unsigned short* __restrict__ WdTb, unsigned short* __restrict__ WscTb,
        unsigned short* __restrict__ w2a, unsigned short* __restrict__ w3a,
        unsigned short* __restrict__ binT)
{
    __shared__ float sh[2][256];
    const int blk = blockIdx.x, tid = threadIdx.x;

    if (blk < 23) {
        const int bin = blk, c = tid;
        WdTb[bin * 128 + c]  = (bin < 22) ? f2bf(W1[c * 236 + 192 + bin]) : (unsigned short)0;
        WscTb[bin * 128 + c] = (bin < 22) ? f2bf(W1[c * 236 + 214 + bin]) : (unsigned short)0;
    } else if (blk < 55) {
        // pack W2/W3 into A-fragment order: entry idx = ct*256 + ks*64 + lane
        // holds W[ct*16 + (lane&15)][ks*32 + (lane>>4)*8 + e]
        const int seg = blk - 23;
        const int isW3 = seg >> 4;
        const int idx = (seg & 15) * 128 + tid;
        const int lane = idx & 63, ks = (idx >> 6) & 3, ct = idx >> 8;
        const float* W = isW3 ? W3 : W2;
        unsigned short* dst = isW3 ? w3a : w2a;
        const float* wp = W + (ct * 16 + (lane & 15)) * 128 + ks * 32 + (lane >> 4) * 8;
        unsigned r0 = (unsigned)f2bf(wp[0]) | ((unsigned)f2bf(wp[1]) << 16);
        unsigned r1 = (unsigned)f2bf(wp[2]) | ((unsigned)f2bf(wp[3]) << 16);
        unsigned r2 = (unsigned)f2bf(wp[4]) | ((unsigned)f2bf(wp[5]) << 16);
        unsigned r3 = (unsigned)f2bf(wp[6]) | ((unsigned)f2bf(wp[7]) << 16);
        uint4 v = { r0, r1, r2, r3 };
        *(uint4*)(dst + idx * 8) = v;
    } else if (blk < 1078) {
        // relTb[d] = bf16( (pos_emb(d) @ W_rp^T + b_rp) @ W1[:,128:192]^T + b1 )
        const int row = blk - 55;
        const float d = (float)(row - 511);
        if (tid < 32) {
            float f = powf(2056.0f, (float)tid * (1.0f / 32.0f));
            float ang = d * 3.14159265358979323846f / f;
            sh[0][tid] = sinf(ang);
            sh[0][tid + 32] = cosf(ang);
        }
        __syncthreads();
        if (tid < 64) {
            const float* wr = Wrp + tid * 64;
            float a = brp[tid];
            #pragma unroll
            for (int k = 0; k < 64; ++k) a += sh[0][k] * wr[k];
            sh[1][tid] = a;
        }
        __syncthreads();
        const float* w = W1 + tid * 236 + 128;
        float a = b1[tid];
        #pragma unroll
        for (int k = 0; k < 64; ++k) a += sh[1][k] * w[k];
        relTb[row * 128 + tid] = f2bf(a);
    } else if (blk < 1590) {
        // p_i = s @ Wsp^T + bsp, two rows per block
        const int half = tid >> 6, ch = tid & 63;
        const int row = (blk - 1078) * 2 + half;
        *(float4*)&sh[half][ch * 4] = *(const float4*)&s[row * 256 + ch * 4];
        __syncthreads();
        const float* w = Wsp + ch * 256;
        float acc = bsp[ch];
        #pragma unroll 8
        for (int k = 0; k < 256; k += 4)
            acc += sh[half][k]*w[k] + sh[half][k+1]*w[k+1] + sh[half][k+2]*w[k+2] + sh[half][k+3]*w[k+3];
        p_i[row * 64 + ch] = acc;
    } else {
        const int pair = (blk - 1590) * 128 + tid;
        const int bi = pair >> 9, j = pair & (NN - 1);
        const int rj = (bi & ~(NN - 1)) + j;
        float ax = t[bi*3+0] - t[rj*3+0];
        float ay = t[bi*3+1] - t[rj*3+1];
        float az = t[bi*3+2] - t[rj*3+2];
        int bD = find_bin(sqrtf(ax*ax + ay*ay + az*az));
        float sx = sct[bi*3+0] - sct[rj*3+0];
        float sy = sct[bi*3+1] - sct[rj*3+1];
        float sz = sct[bi*3+2] - sct[rj*3+2];
        int bS = find_bin(sqrtf(sx*sx + sy*sy + sz*sz));
        binT[pair] = (unsigned short)(bD | (bS << 5));
    }
}

// ---- qL/qR (bf16): per-node contributions through W1 cols [0:64)/[64:128) ----
__global__ __launch_bounds__(128) void k_ql(const float* __restrict__ p_i,
        const float* __restrict__ W1,
        unsigned short* __restrict__ qLb, unsigned short* __restrict__ qRb)
{
    __shared__ float pr[64];
    const int row = blockIdx.x, tid = threadIdx.x;
    if (tid < 16) *(float4*)&pr[tid * 4] = *(const float4*)&p_i[row * 64 + tid * 4];
    __syncthreads();
    const float* w = W1 + tid * 236;
    float aL = 0.f, aR = 0.f;
    #pragma unroll
    for (int k = 0; k < 64; ++k) { aL += pr[k] * w[k]; aR += pr[k] * w[64 + k]; }
    qLb[row * 128 + tid] = f2bf(aL);
    qRb[row * 128 + tid] = f2bf(aR);
}

// LDS layout (bytes):
#define H1_OFF  0        // 64 rows x 256B bf16, XOR-swizzled; reused as out-stage
#define H2_OFF  16384    // 64 rows x 256B bf16, XOR-swizzled; reused as out-stage
#define LNP_OFF 32768    // 64 rows x 48B (4 wc float2 partials, stride 12 f)
#define SMEM_SZ 35840

// ---- main fused kernel (R8 structure): 8 waves = 2 row-halves x 4 ch-quarters;
//      wave holds 2 ct weight tiles per GEMM in regs; h1/h2 in LDS; LN via
//      cross-wave partials; LDS-bounced full-line stores. XCD-chunked block
//      swizzle for per-XCD L2 table locality. ----
__global__ __launch_bounds__(512, 4) void k_main(
    const float* __restrict__ pmask,
    const unsigned short* __restrict__ qLb, const unsigned short* __restrict__ qRb,
    const unsigned short* __restrict__ relTb, const unsigned short* __restrict__ WdTb,
    const unsigned short* __restrict__ WscTb, const unsigned short* __restrict__ binT,
    const unsigned short* __restrict__ w2a, const unsigned short* __restrict__ w3a,
    const float* __restrict__ b2, const float* __restrict__ b3,
    const float* __restrict__ lng, const float* __restrict__ lnb,
    float* __restrict__ out)
{
    __shared__ __align__(16) char smem[SMEM_SZ];

    const int tid  = threadIdx.x;
    const int l    = tid & 63;
    const int w    = tid >> 6;
    const int wr   = w >> 2;         // row half (32 rows)
    const int wc   = w & 3;          // channel quarter (32 ch = 2 ct)
    const int jloc = l & 15;
    const int gq   = l >> 4;

    // XCD-chunked swizzle: HW assigns blockIdx round-robin over 8 XCDs;
    // remap so XCD x serves 1024 consecutive logical tiles (8192 % 8 == 0).
    const int blk   = (blockIdx.x & 7) * 1024 + (blockIdx.x >> 3);
    const int bi    = blk >> 3;              // b*512 + i
    const int i     = bi & (NN - 1);
    const int bbase = bi & ~(NN - 1);
    const int j0    = (blk & 7) * 64;        // block covers 64 rows

    // ---- per-wave weight fragments (2 ct per GEMM, in registers) ----
    bf16x8 w2r[2][4], w3r[2][4];
    #pragma unroll
    for (int cc = 0; cc < 2; ++cc)
        #pragma unroll
        for (int ks = 0; ks < 4; ++ks) {
            const int fi = ((wc * 2 + cc) * 256 + ks * 64 + l) * 8;
            w2r[cc][ks] = *(const bf16x8*)(w2a + fi);
            w3r[cc][ks] = *(const bf16x8*)(w3a + fi);
        }
    float maskv[2];
    #pragma unroll
    for (int rt = 0; rt < 2; ++rt)
        maskv[rt] = pmask[(size_t)bi * NN + j0 + wr * 32 + rt * 16 + jloc];

    // ---- build h1 = relu(qL+qR+relT+Wd[bin]+Wsc[bin]) into LDS (bf16) ----
    {
        const int r = tid >> 3, q = tid & 7;        // row 0..63, ch-octet 0..7
        const unsigned bv = binT[bi * NN + j0 + r];
        const int bD = bv & 31, bS = (int)(bv >> 5);
        const unsigned short* qLp = qLb + (size_t)bi * 128;
        const unsigned short* qRp = qRb + (size_t)(bbase + j0 + r) * 128;
        const unsigned short* rTp = relTb + (size_t)(i - (j0 + r) + NN - 1) * 128;
        const unsigned short* dTp = WdTb + bD * 128;
        const unsigned short* sTp = WscTb + bS * 128;
        const int hswz = (r & 7) << 4;
        #pragma unroll
        for (int u = 0; u < 2; ++u) {
            const int c0 = q * 16 + u * 8;
            uint4 A = *(const uint4*)(qLp + c0);
            uint4 B = *(const uint4*)(qRp + c0);
            uint4 C = *(const uint4*)(rTp + c0);
            uint4 D = *(const uint4*)(dTp + c0);
            uint4 E = *(const uint4*)(sTp + c0);
            uint4 P;
            P.x = pk2(A.x, B.x, C.x, D.x, E.x);
            P.y = pk2(A.y, B.y, C.y, D.y, E.y);
            P.z = pk2(A.z, B.z, C.z, D.z, E.z);
            P.w = pk2(A.w, B.w, C.w, D.w, E.w);
            *(uint4*)(smem + H1_OFF + ((r * 256 + c0 * 2) ^ hswz)) = P;
        }
    }
    __syncthreads();   // bar1: h1 complete

    const int rswz = (jloc & 7) << 4;

    // ---- GEMM2: wave computes 32 rows x 32 ch; each B-frag feeds 2 MFMA ----
    #pragma unroll
    for (int rt = 0; rt < 2; ++rt) {
        const int rowb = (wr * 32 + rt * 16 + jloc) * 256;
        f32x4 a2[2] = { {0.f,0.f,0.f,0.f}, {0.f,0.f,0.f,0.f} };
        #pragma unroll
        for (int ks = 0; ks < 4; ++ks) {
            bf16x8 bfr = *(bf16x8*)(smem + H1_OFF + ((rowb + ks * 64 + gq * 16) ^ rswz));
            a2[0] = __builtin_amdgcn_mfma_f32_16x16x32_bf16(w2r[0][ks], bfr, a2[0], 0, 0, 0);
            a2[1] = __builtin_amdgcn_mfma_f32_16x16x32_bf16(w2r[1][ks], bfr, a2[1], 0, 0, 0);
        }
        #pragma unroll
        for (int cc = 0; cc < 2; ++cc) {
            const int c = wc * 32 + cc * 16 + gq * 4;
            float4 bb = *(const float4*)(b2 + c);
            float y0 = fmaxf(a2[cc][0] + bb.x, 0.0f);
            float y1 = fmaxf(a2[cc][1] + bb.y, 0.0f);
            float y2 = fmaxf(a2[cc][2] + bb.z, 0.0f);
            float y3 = fmaxf(a2[cc][3] + bb.w, 0.0f);
            uint2 pk;
            pk.x = (unsigned)f2bf(y0) | ((unsigned)f2bf(y1) << 16);
            pk.y = (unsigned)f2bf(y2) | ((unsigned)f2bf(y3) << 16);
            *(uint2*)(smem + H2_OFF + ((rowb + c * 2) ^ rswz)) = pk;
        }
    }
    __syncthreads();   // bar2: h2 complete

    // ---- GEMM3 + cross-wave LN partials ----
    f32x4 acc3[2][2];
    float* lnp = (float*)(smem + LNP_OFF);
    #pragma unroll
    for (int rt = 0; rt < 2; ++rt) {
        const int rowb = (wr * 32 + rt * 16 + jloc) * 256;
        f32x4 a3[2] = { {0.f,0.f,0.f,0.f}, {0.f,0.f,0.f,0.f} };
        #pragma unroll
        for (int ks = 0; ks < 4; ++ks) {
            bf16x8 bfr = *(bf16x8*)(smem + H2_OFF + ((rowb + ks * 64 + gq * 16) ^ rswz));
            a3[0] = __builtin_amdgcn_mfma_f32_16x16x32_bf16(w3r[0][ks], bfr, a3[0], 0, 0, 0);
            a3[1] = __builtin_amdgcn_mfma_f32_16x16x32_bf16(w3r[1][ks], bfr, a3[1], 0, 0, 0);
        }
        float s1 = 0.f, s2 = 0.f;
        #pragma unroll
        for (int cc = 0; cc < 2; ++cc) {
            const int c = wc * 32 + cc * 16 + gq * 4;
            float4 bb = *(const float4*)(b3 + c);
            a3[cc][0] += bb.x; a3[cc][1] += bb.y;
            a3[cc][2] += bb.z; a3[cc][3] += bb.w;
            acc3[cc][rt] = a3[cc];
            #pragma unroll
            for (int r = 0; r < 4; ++r) { float v = a3[cc][r]; s1 += v; s2 += v * v; }
        }
        s1 += __shfl_xor(s1, 16); s2 += __shfl_xor(s2, 16);
        s1 += __shfl_xor(s1, 32); s2 += __shfl_xor(s2, 32);
        if (l < 16) {
            const int row = wr * 32 + rt * 16 + jloc;
            *(float2*)(lnp + row * 12 + wc * 2) = make_float2(s1, s2);
        }
    }
    __syncthreads();   // bar3: LN partials done; h1/h2 reads drained

    // ---- finish LN, scale, mask, write to out-stage (swizzled slots) ----
    #pragma unroll
    for (int rt = 0; rt < 2; ++rt) {
        const int row = wr * 32 + rt * 16 + jloc;
        float4 v0 = *(float4*)(lnp + row * 12);
        float4 v1 = *(float4*)(lnp + row * 12 + 4);
        const float s1 = v0.x + v0.z + v1.x + v1.z;
        const float s2 = v0.y + v0.w + v1.y + v1.w;
        const float mean = s1 * (1.0f / 128.0f);
        const float var  = s2 * (1.0f / 128.0f) - mean * mean;
        const float rstd = rsqrtf(var + 1e-5f);
        const float mk = maskv[rt];
        #pragma unroll
        for (int cc = 0; cc < 2; ++cc) {
            const int c = wc * 32 + cc * 16 + gq * 4;
            float4 g4  = *(const float4*)(lng + c);
            float4 be4 = *(const float4*)(lnb + c);
            f32x4 a3 = acc3[cc][rt];
            f32x4 o;
            o[0] = ((a3[0] - mean) * rstd * g4.x + be4.x) * mk;
            o[1] = ((a3[1] - mean) * rstd * g4.y + be4.y) * mk;
            o[2] = ((a3[2] - mean) * rstd * g4.z + be4.z) * mk;
            o[3] = ((a3[3] - mean) * rstd * g4.w + be4.w) * mk;
            const int slot = (wc * 8 + cc * 4 + gq) ^ (row & 31);
            *(f32x4*)(smem + row * 512 + slot * 16) = o;
        }
    }
    __syncthreads();   // bar4: out-stage complete

    // ---- block-wide coalesced copy: 4 x 8KB, 1KB contiguous per wave ----
    float* ob = out + ((size_t)(bi * NN + j0)) * 128;
    #pragma unroll
    for (int it = 0; it < 4; ++it) {
        const int boff = it * 8192 + tid * 16;      // linear byte offset
        const int row  = boff >> 9;
        const int slot = (boff >> 4) & 31;
        const int sslt = slot ^ (row & 31);
        f32x4 v = *(f32x4*)(smem + row * 512 + sslt * 16);
        __builtin_nontemporal_store(v, (f32x4*)(ob + (boff >> 2)));
    }
}

extern "C" void kernel_launch(void* const* d_in, const int* in_sizes, int n_in,
                              void* d_out, int out_size, void* d_ws, size_t ws_size,
                              hipStream_t stream)
{
    const float* s   = (const float*)d_in[0];
    const float* t   = (const float*)d_in[1];
    const float* sct = (const float*)d_in[2];
    const float* pm  = (const float*)d_in[3];
    const float* Wsp = (const float*)d_in[4];
    const float* bsp = (const float*)d_in[5];
    const float* Wrp = (const float*)d_in[6];
    const float* brp = (const float*)d_in[7];
    const float* W1  = (const float*)d_in[8];
    const float* b1  = (const float*)d_in[9];
    const float* W2  = (const float*)d_in[10];
    const float* b2  = (const float*)d_in[11];
    const float* W3  = (const float*)d_in[12];
    const float* b3  = (const float*)d_in[13];
    const float* lng = (const float*)d_in[14];
    const float* lnb = (const float*)d_in[15];

    float* ws = (float*)d_ws;
    float*          p_i   = ws;                                   // 65536 f
    unsigned short* qLb   = (unsigned short*)(ws + 65536);        // 131072 u16
    unsigned short* qRb   = (unsigned short*)(ws + 131072);       // 131072 u16
    unsigned short* relTb = (unsigned short*)(ws + 196608);       // 130944 u16
    unsigned short* WdTb  = (unsigned short*)(ws + 262144);       // 2944 u16
    unsigned short* WscTb = (unsigned short*)(ws + 263616);       // 2944 u16
    unsigned short* w2a   = (unsigned short*)(ws + 265088);       // 16384 u16
    unsigned short* w3a   = (unsigned short*)(ws + 273280);       // 16384 u16
    unsigned short* binT  = (unsigned short*)(ws + 281472);       // 524288 u16

    k_prep<<<5686, 128, 0, stream>>>(s, t, sct, Wsp, bsp, Wrp, brp, W1, b1, W2, W3,
                                     p_i, relTb, WdTb, WscTb, w2a, w3a, binT);
    k_ql<<<1024, 128, 0, stream>>>(p_i, W1, qLb, qRb);
    k_main<<<8192, 512, 0, stream>>>(pm, qLb, qRb, relTb, WdTb, WscTb, binT,
                                     w2a, w3a, b2, b3, lng, lnb, (float*)d_out);
}